// Round 1
// 114.581 us; speedup vs baseline: 1.0265x; 1.0265x over previous
//
#include <hip/hip_runtime.h>
#include <hip/hip_bf16.h>
#include <math.h>

#define BB 64
#define QQ 900
#define GG 100
#define NCLS 10
#define CP1 11

#define STRIDE 960   // 64*15: every lane owns exactly KPL columns; cols 900..959 are +inf pads
#define KPL 15
#define NT 512
#define NW 8
#define QMASK 255    // ring queue; live entries <= n <= 100 < 256
#define ROUND_CAP 20000

#define NCH 8        // q-chunks in cost kernel
#define QCH 128      // queries per chunk (8*128 = 1024 covers 960 stride)

#define CLS_W 2.0f
#define L1_W 5.0f
#define GIOU_W 2.0f

struct Accum {
  double wnll, wt, l1, gl;
  int nm, counter;
  int pad[6];
};

// ---------------- cost matrix + per-chunk row-min partials ----------------
// grid (NCH, BB) x 256 threads. Threads split as 128 q x 2 g-halves.
// Rows g >= n (invalid gts) are never read by jv -> skip compute AND write.
// Each block also emits per-row (m1, m2, argmin) over its q-chunk via an
// LDS transpose (pad +1 -> conflict-free) + per-row serial scan.
__global__ __launch_bounds__(256) void cost_kernel(
    const float* __restrict__ logits, const float* __restrict__ pboxes,
    const int* __restrict__ gcls, const float* __restrict__ gboxes,
    float* __restrict__ cost, float4* __restrict__ part, Accum* acc) {
  const int b = blockIdx.y;
  const int chunk = blockIdx.x;
  const int tid = threadIdx.x;
  const int ql = tid & (QCH - 1);
  const int gh = tid >> 7;               // 0: g in [0,50), 1: g in [50,100)
  const int q = chunk * QCH + ql;

  if (chunk == 0 && b == 0 && tid == 0) {
    acc->wnll = 0.0; acc->wt = 0.0; acc->l1 = 0.0; acc->gl = 0.0;
    acc->nm = 0; acc->counter = 0;
  }

  __shared__ float s_gb[GG * 4];
  __shared__ int   s_gc[GG];
  __shared__ float s_prob[QCH * 13];
  __shared__ float s_c[GG][QCH + 1];     // +1 pad: bank = (g+ql)%32, conflict-free both axes
  __shared__ int   sh_n;

  if (tid == 0) sh_n = 0;
  __syncthreads();

  for (int i = tid; i < GG * 4; i += 256) s_gb[i] = gboxes[b * GG * 4 + i];
  for (int i = tid; i < GG; i += 256) {
    const int v = gcls[b * GG + i];
    s_gc[i] = v;
    if (v >= 0) atomicAdd(&sh_n, 1);
  }

  float pcx = 0.f, pcy = 0.f, pw = 0.f, ph = 0.f;
  if (q < QQ) {
    const float* pb = pboxes + ((size_t)b * QQ + q) * 4;
    pcx = pb[0]; pcy = pb[1]; pw = pb[2]; ph = pb[3];
    if (gh == 0) {  // softmax once per q, shared with the other g-half
      const float* lg = logits + ((size_t)b * QQ + q) * CP1;
      float l[CP1];
      float mx = -1e30f;
      for (int c = 0; c < CP1; ++c) { l[c] = lg[c]; mx = fmaxf(mx, l[c]); }
      float se = 0.f;
      for (int c = 0; c < CP1; ++c) { l[c] = expf(l[c] - mx); se += l[c]; }
      const float inv = 1.0f / se;
      for (int c = 0; c < NCLS; ++c) s_prob[ql * 13 + c] = l[c] * inv;
    }
  }
  __syncthreads();
  const int sn = sh_n;

  const float px1 = pcx - 0.5f * pw, py1 = pcy - 0.5f * ph;
  const float px2 = pcx + 0.5f * pw, py2 = pcy + 0.5f * ph;
  const float pa = fmaxf(px2 - px1, 0.f) * fmaxf(py2 - py1, 0.f);

  float* crow = cost + ((size_t)b * GG) * STRIDE + q;
  const int g0 = gh * 50;
  const int gend = (g0 + 50 < sn) ? g0 + 50 : sn;
  for (int g = g0; g < gend; ++g) {
    float cv = 3e38f;
    if (q < QQ) {
      int cls = s_gc[g];
      cls = cls < 0 ? 0 : (cls > NCLS - 1 ? NCLS - 1 : cls);
      const float cc = -s_prob[ql * 13 + cls];
      const float gcx = s_gb[g * 4 + 0], gcy = s_gb[g * 4 + 1];
      const float gw  = s_gb[g * 4 + 2], gh2 = s_gb[g * 4 + 3];
      const float l1 = fabsf(pcx - gcx) + fabsf(pcy - gcy) + fabsf(pw - gw) + fabsf(ph - gh2);
      const float gx1 = gcx - 0.5f * gw, gy1 = gcy - 0.5f * gh2;
      const float gx2 = gcx + 0.5f * gw, gy2 = gcy + 0.5f * gh2;
      const float ga = fmaxf(gx2 - gx1, 0.f) * fmaxf(gy2 - gy1, 0.f);
      const float ltx = fmaxf(px1, gx1), lty = fmaxf(py1, gy1);
      const float rbx = fminf(px2, gx2), rby = fminf(py2, gy2);
      const float iw = fmaxf(rbx - ltx, 0.f), ih = fmaxf(rby - lty, 0.f);
      const float inter = iw * ih;
      const float uni = pa + ga - inter;
      const float iou = inter / fmaxf(uni, 1e-6f);
      const float ex1 = fminf(px1, gx1), ey1 = fminf(py1, gy1);
      const float ex2 = fmaxf(px2, gx2), ey2 = fmaxf(py2, gy2);
      const float ew = fmaxf(ex2 - ex1, 0.f), eh = fmaxf(ey2 - ey1, 0.f);
      const float enc = ew * eh;
      const float giou = iou - (enc - uni) / fmaxf(enc, 1e-6f);
      cv = CLS_W * cc + L1_W * l1 - GIOU_W * giou;
      crow[(size_t)g * STRIDE] = cv;
    } else if (q < STRIDE) {
      crow[(size_t)g * STRIDE] = 1e30f;   // pad columns: Phase D scans them
    }
    s_c[g][ql] = cv;                       // 3e38 beyond QQ: excluded from mins
  }
  __syncthreads();

  // per-row (m1, m2, argmin) over this chunk: thread t = row, serial scan, 2 ILP chains
  if (tid < sn) {
    const int kmax = (chunk == NCH - 1) ? (QQ - (NCH - 1) * QCH) : QCH;  // 4 or 128
    float m1 = 3e38f, m2 = 3e38f, n1 = 3e38f, n2 = 3e38f;
    int j1 = 0x7FFFFFFF, i1 = 0x7FFFFFFF;
    const int ka = kmax < 64 ? kmax : 64;
    for (int k = 0; k < ka; ++k) {
      const float c = s_c[tid][k];
      if (c < m1) { m2 = m1; m1 = c; j1 = 1 + chunk * QCH + k; }
      else if (c < m2) m2 = c;
    }
    for (int k = 64; k < kmax; ++k) {
      const float c = s_c[tid][k];
      if (c < n1) { n2 = n1; n1 = c; i1 = 1 + chunk * QCH + k; }
      else if (c < n2) n2 = c;
    }
    if (n1 < m1) { m2 = fminf(m1, n2); m1 = n1; j1 = i1; }
    else m2 = fminf(m2, n1);
    part[((size_t)b * NCH + chunk) * QCH + tid] = make_float4(m1, m2, __int_as_float(j1), 0.f);
  }
}

// ---------------- jv: partial-combine rowmin + regret-greedy + pipelined ARR + fused loss ----
__global__ __launch_bounds__(NT) void jv_kernel(
    const float* __restrict__ logits, const float* __restrict__ pboxes,
    const int* __restrict__ gcls, const float* __restrict__ gboxes,
    const float* __restrict__ cost, const float4* __restrict__ part,
    Accum* acc, float* out) {
  const int b = blockIdx.x;
  const int tid = threadIdx.x;
  const int lane = tid & 63;
  const int w = tid >> 6;

  __shared__ float vl[STRIDE + 2];      // column duals (f32), <= 0
  __shared__ int   p[QQ + 1];           // column -> owning row (1-based), 0 = free
  __shared__ unsigned long long way64[STRIDE + 2];  // regret-max claim keys
  __shared__ float m1l[GG + 1], m2l[GG + 1];
  __shared__ int   aminl[GG + 1];
  __shared__ int   s_gc[GG];
  __shared__ int   queue[QMASK + 1];
  __shared__ int   sh_n, sh_qtail;
  __shared__ double r0[NW], r1[NW], r2[NW], r3[NW];
  __shared__ int r4[NW];
  __shared__ float s_lse[QQ], s_mx[QQ];  // Phase-E softmax stats, filled during Phase D

  if (tid == 0) { sh_n = 0; sh_qtail = 0; }
  for (int j = tid; j <= QQ; j += NT) p[j] = 0;
  for (int j = tid; j < STRIDE + 2; j += NT) { vl[j] = 0.f; way64[j] = 0ull; }
  if (tid < GG) s_gc[tid] = gcls[b * GG + tid];
  __syncthreads();
  if (tid < GG && s_gc[tid] >= 0) atomicAdd(&sh_n, 1);
  __syncthreads();
  const int n = sh_n;
  const float* Cb = cost + (size_t)b * GG * STRIDE;

  // ---- Phase B: combine per-chunk partials from cost_kernel (4.8 KB instead of 384 KB) ----
  for (int r = tid; r < n; r += NT) {
    float m1 = 3e38f, m2 = 3e38f;
    int j1 = 0x7FFFFFFF;
#pragma unroll
    for (int ch = 0; ch < NCH; ++ch) {
      const float4 pr = part[((size_t)b * NCH + ch) * QCH + r];
      const float pm1 = pr.x, pm2 = pr.y;
      if (pm1 < m1) { m2 = fminf(m1, pm2); m1 = pm1; j1 = __float_as_int(pr.z); }
      else m2 = fminf(m2, pm1);
    }
    m1l[r] = m1; m2l[r] = m2; aminl[r] = j1;
  }
  __syncthreads();

  // ---- Phase C: greedy claim, contested columns go to max regret (fewer cascades) ----
  if (tid < n) {
    const float regret = m2l[tid] - m1l[tid];   // >= 0: non-neg f32 bits are monotone
    const unsigned long long key =
        ((unsigned long long)__float_as_uint(regret) << 20) | (unsigned long long)(tid + 1);
    atomicMax(&way64[aminl[tid]], key);
  }
  __syncthreads();
  if (tid < n) {
    const int j1 = aminl[tid];
    if ((int)(way64[j1] & 0xFFFFFu) == tid + 1) {  // winner: u=m2, vl[j1] = m1 - m2 (<= 0)
      p[j1] = tid + 1;
      vl[j1] = m1l[tid] - m2l[tid];
    } else {                                       // loser: u=m1 stays feasible; queue for ARR
      const int t0 = atomicAdd(&sh_qtail, 1);
      queue[t0 & QMASK] = tid + 1;
    }
  }
  __syncthreads();

  // ---- Phase D: single-wave ARR (wave 0); waves 1-7 precompute Phase-E softmax stats ----
  if (w == 0) {
    float v[KPL];
#pragma unroll
    for (int k = 0; k < KPL; ++k) v[k] = vl[1 + lane + (k << 6)];
    int head = 0, tail = sh_qtail, rounds = 0;

    float bufA[KPL], bufB[KPL], bufC[KPL];
    int ia = -1, ib = -1, ic = -1;

    auto loadrow = [&](float* buf, int rid) {
      const float* Cr = Cb + (size_t)(rid - 1) * STRIDE + lane;
#pragma unroll
      for (int k = 0; k < KPL; ++k) buf[k] = Cr[k << 6];
    };
    auto do_step = [&](float* rc, int i) {
      // scan 960 reduced costs: two independent chains + merge (ILP)
      float m1 = 3e38f, m2 = 3e38f, n1 = 3e38f, n2 = 3e38f;
      int j1 = 0x7FFFFFFF, i1 = 0x7FFFFFFF;
#pragma unroll
      for (int k = 0; k < 8; ++k) {
        const float c = rc[k] - v[k];
        if (c < m1) { m2 = m1; m1 = c; j1 = 1 + lane + (k << 6); }
        else if (c < m2) m2 = c;
      }
#pragma unroll
      for (int k = 8; k < KPL; ++k) {
        const float c = rc[k] - v[k];
        if (c < n1) { n2 = n1; n1 = c; i1 = 1 + lane + (k << 6); }
        else if (c < n2) n2 = c;
      }
      if (n1 < m1) { m2 = fminf(m1, n2); m1 = n1; j1 = i1; }
      else m2 = fminf(m2, n1);
      for (int m = 1; m < 64; m <<= 1) {
        const float o1 = __shfl_xor(m1, m);
        const float o2 = __shfl_xor(m2, m);
        const int oj = __shfl_xor(j1, m);
        if (o1 < m1) { m2 = fminf(m1, o2); m1 = o1; j1 = oj; }
        else m2 = fminf(m2, o1);
      }
      float d = m2 - m1;
      if (d < 0.f) d = 0.f;
      const int c0 = j1 - 1;
      if ((c0 & 63) == lane) {   // strict decrease of claimed column's dual
        const int kk = c0 >> 6;
        const float ov = v[kk];
        float nv = ov - d;
        if (!(nv < ov)) nv = nextafterf(ov, -3e38f);
        v[kk] = nv;
      }
      const int k0 = p[j1];      // broadcast LDS read
      p[j1] = i;                 // same-addr write, one lane wins
      head++;
      if (k0 > 0) {
        if (lane == 0) queue[tail & QMASK] = k0;
        tail++;
      }
    };

    // prime the pipeline (rows are immutable: any prefetch depth is correct)
    if (head < tail)     { ia = queue[head & QMASK];       loadrow(bufA, ia); }
    if (head + 1 < tail) { ib = queue[(head + 1) & QMASK]; loadrow(bufB, ib); }
    if (head + 2 < tail) { ic = queue[(head + 2) & QMASK]; loadrow(bufC, ic); }

    while (head < tail && rounds < ROUND_CAP) {
      // step A
      if (ia < 0) { ia = queue[head & QMASK]; loadrow(bufA, ia); }
      do_step(bufA, ia);
      ia = -1;
      if (head + 2 < tail) { ia = queue[(head + 2) & QMASK]; loadrow(bufA, ia); }
      rounds++;
      if (!(head < tail && rounds < ROUND_CAP)) break;
      // step B
      if (ib < 0) { ib = queue[head & QMASK]; loadrow(bufB, ib); }
      do_step(bufB, ib);
      ib = -1;
      if (head + 2 < tail) { ib = queue[(head + 2) & QMASK]; loadrow(bufB, ib); }
      rounds++;
      if (!(head < tail && rounds < ROUND_CAP)) break;
      // step C
      if (ic < 0) { ic = queue[head & QMASK]; loadrow(bufC, ic); }
      do_step(bufC, ic);
      ic = -1;
      if (head + 2 < tail) { ic = queue[(head + 2) & QMASK]; loadrow(bufC, ic); }
      rounds++;
    }
    // cap leftovers stay unmatched: graceful tiny loss shift (expected: never)
  } else {
    // waves 1-7: per-q max + logsumexp, overlapped with wave-0's serial ARR.
    // Same float op order as the old Phase E -> bitwise-identical logp later.
    for (int qq = tid - 64; qq < QQ; qq += (NT - 64)) {
      const float* lg = logits + ((size_t)b * QQ + qq) * CP1;
      float l[CP1];
      float mx = -1e30f;
      for (int c = 0; c < CP1; ++c) { l[c] = lg[c]; mx = fmaxf(mx, l[c]); }
      float se = 0.f;
      for (int c = 0; c < CP1; ++c) se += expf(l[c] - mx);
      s_mx[qq] = mx;
      s_lse[qq] = logf(se);
    }
  }
  __syncthreads();

  // ---- Phase E: fused loss; softmax stats precomputed, 1 gather per query ----
  double wnll = 0.0, wt = 0.0, l1d = 0.0, gld = 0.0;
  int nm = 0;
  for (int q = tid; q < QQ; q += NT) {
    const int idx = b * QQ + q;
    const int g = p[q + 1] - 1;   // row -> gt index (valid gts are a prefix)
    const int t = (g >= 0) ? s_gc[g] : NCLS;
    const float lt = logits[(size_t)idx * CP1 + t];
    const float logp = (lt - s_mx[q]) - s_lse[q];
    const float wgt = (t == NCLS) ? 0.1f : 1.0f;
    wnll += (double)(wgt * (-logp));
    wt += (double)wgt;
    if (g >= 0) {
      nm += 1;
      const float* pb = pboxes + (size_t)idx * 4;
      const float* gb = gboxes + ((size_t)b * GG + g) * 4;
      const float pcx = pb[0], pcy = pb[1], pw = pb[2], ph = pb[3];
      const float gcx = gb[0], gcy = gb[1], gw = gb[2], gh = gb[3];
      const float l1 = fabsf(pcx - gcx) + fabsf(pcy - gcy) + fabsf(pw - gw) + fabsf(ph - gh);
      const float px1 = pcx - 0.5f * pw, py1 = pcy - 0.5f * ph;
      const float px2 = pcx + 0.5f * pw, py2 = pcy + 0.5f * ph;
      const float gx1 = gcx - 0.5f * gw, gy1 = gcy - 0.5f * gh;
      const float gx2 = gcx + 0.5f * gw, gy2 = gcy + 0.5f * gh;
      const float pa = fmaxf(px2 - px1, 0.f) * fmaxf(py2 - py1, 0.f);
      const float ga = fmaxf(gx2 - gx1, 0.f) * fmaxf(gy2 - gy1, 0.f);
      const float ltx = fmaxf(px1, gx1), lty = fmaxf(py1, gy1);
      const float rbx = fminf(px2, gx2), rby = fminf(py2, gy2);
      const float iw = fmaxf(rbx - ltx, 0.f), ih = fmaxf(rby - lty, 0.f);
      const float inter = iw * ih;
      const float uni = pa + ga - inter;
      const float iou = inter / fmaxf(uni, 1e-6f);
      const float ex1 = fminf(px1, gx1), ey1 = fminf(py1, gy1);
      const float ex2 = fmaxf(px2, gx2), ey2 = fmaxf(py2, gy2);
      const float ew = fmaxf(ex2 - ex1, 0.f), eh = fmaxf(ey2 - ey1, 0.f);
      const float enc = ew * eh;
      const float giou = iou - (enc - uni) / fmaxf(enc, 1e-6f);
      l1d += (double)l1;
      gld += (double)(1.0f - giou);
    }
  }

  for (int off = 32; off; off >>= 1) {
    wnll += __shfl_down(wnll, off);
    wt   += __shfl_down(wt, off);
    l1d  += __shfl_down(l1d, off);
    gld  += __shfl_down(gld, off);
    nm   += __shfl_down(nm, off);
  }
  if (lane == 0) { r0[w] = wnll; r1[w] = wt; r2[w] = l1d; r3[w] = gld; r4[w] = nm; }
  __syncthreads();
  if (tid == 0) {
    for (int x = 1; x < NW; ++x) { wnll += r0[x]; wt += r1[x]; l1d += r2[x]; gld += r3[x]; nm += r4[x]; }
    atomicAdd(&acc->wnll, wnll);
    atomicAdd(&acc->wt, wt);
    atomicAdd(&acc->l1, l1d);
    atomicAdd(&acc->gl, gld);
    atomicAdd(&acc->nm, nm);
    __threadfence();
    const int ticket = atomicAdd(&acc->counter, 1);
    if (ticket == BB - 1) {
      const double fw = atomicAdd(&acc->wnll, 0.0);
      const double fwt = atomicAdd(&acc->wt, 0.0);
      const double fl1 = atomicAdd(&acc->l1, 0.0);
      const double fgl = atomicAdd(&acc->gl, 0.0);
      int fnm = atomicAdd(&acc->nm, 0);
      if (fnm < 1) fnm = 1;
      const double loss = (double)CLS_W * (fw / fwt) +
                          ((double)L1_W * fl1 + (double)GIOU_W * fgl) / (double)fnm;
      out[0] = (float)loss;
    }
  }
}

extern "C" void kernel_launch(void* const* d_in, const int* in_sizes, int n_in,
                              void* d_out, int out_size, void* d_ws, size_t ws_size,
                              hipStream_t stream) {
  const float* logits = (const float*)d_in[0];
  const float* pboxes = (const float*)d_in[1];
  const int*   gcls   = (const int*)d_in[2];
  const float* gboxes = (const float*)d_in[3];

  char* ws = (char*)d_ws;
  Accum* acc = (Accum*)ws;                                  // 64 B, inited in cost_kernel
  float4* part = (float4*)(ws + 4096);                      // 64*8*128 float4 = 1 MB
  float* cost = (float*)(ws + 4096 + (size_t)BB * NCH * QCH * sizeof(float4));  // ~24.6 MB

  cost_kernel<<<dim3(NCH, BB), 256, 0, stream>>>(logits, pboxes, gcls, gboxes, cost, part, acc);
  jv_kernel<<<BB, NT, 0, stream>>>(logits, pboxes, gcls, gboxes, cost, part, acc, (float*)d_out);
}